// Round 1
// baseline (5799.844 us; speedup 1.0000x reference)
//
#include <hip/hip_runtime.h>
#include <hip/hip_bf16.h>

#define B_ 2048
#define T_ 128
#define F_ 64
#define U_ 512
#define FOURU 2048
#define OUTS 32
#define NSTEP 159
#define ROWS 128      // batch rows per group
#define COLSB 128     // z cols per block (4 gates x 32 units)
#define KTOT 576      // 64 (x) + 512 (h)
#define LDSTR 584     // padded LDS col stride (elements) -> bank-balanced

typedef __attribute__((ext_vector_type(8))) short bf16x8;
typedef __attribute__((ext_vector_type(4))) float f32x4;

// workspace layout (bytes)
#define OFF_CNT   0
#define OFF_HBUF  4096
#define OFF_WT    (OFF_HBUF + 2*B_*U_*2)
#define OFF_WDEC  (OFF_WT + FOURU*KTOT*2)
#define OFF_DWT   (OFF_WDEC + FOURU*U_*2)
#define OFF_BDEC  (OFF_DWT + F_*U_*2)
#define OFF_XBF   (OFF_BDEC + FOURU*4)
#define WS_TOTAL  (OFF_XBF + (size_t)T_*B_*F_*2)

__device__ __forceinline__ short f2bf(float f) {
  union { float f; unsigned u; } a; a.f = f;
  unsigned u = a.u;
  unsigned r = u + 0x7FFFu + ((u >> 16) & 1u);  // RNE
  return (short)(r >> 16);
}
__device__ __forceinline__ float sigm(float x){ return 1.0f/(1.0f+__expf(-x)); }
__device__ __forceinline__ float tanh_(float x){ return 1.0f - 2.0f/(1.0f+__expf(2.0f*x)); }

// ---------------- prep kernels ----------------
__global__ void prep_wt(const float* __restrict__ Wx, const float* __restrict__ Wh,
                        short* __restrict__ Wt) {
  int idx = blockIdx.x*256 + threadIdx.x;
  if (idx >= FOURU*KTOT) return;
  int c = idx / KTOT, k = idx % KTOT;
  float v = (k < F_) ? Wx[(size_t)k*FOURU + c] : Wh[(size_t)(k-F_)*FOURU + c];
  Wt[idx] = f2bf(v);
}
__global__ void prep_wdec(const float* __restrict__ Wh, const float* __restrict__ Wx,
                          const float* __restrict__ Dw, short* __restrict__ Wdec) {
  int idx = blockIdx.x*256 + threadIdx.x;
  if (idx >= FOURU*U_) return;
  int c = idx / U_, u = idx % U_;
  float a = Wh[(size_t)u*FOURU + c];
  for (int f=0; f<F_; ++f) a += Dw[u*F_ + f] * Wx[(size_t)f*FOURU + c];
  Wdec[idx] = f2bf(a);
}
__global__ void prep_bdec(const float* __restrict__ bv, const float* __restrict__ db,
                          const float* __restrict__ Wx, float* __restrict__ bdec) {
  int c = blockIdx.x*256 + threadIdx.x;
  if (c >= FOURU) return;
  float a = bv[c];
  for (int f=0; f<F_; ++f) a += db[f]*Wx[(size_t)f*FOURU + c];
  bdec[c] = a;
}
__global__ void prep_dwt(const float* __restrict__ Dw, short* __restrict__ Dwt) {
  int idx = blockIdx.x*256 + threadIdx.x;
  if (idx >= F_*U_) return;
  int f = idx / U_, u = idx % U_;
  Dwt[idx] = f2bf(Dw[u*F_ + f]);
}
__global__ void prep_x(const float* __restrict__ in, short* __restrict__ xbf) {
  int idx = blockIdx.x*256 + threadIdx.x;
  if (idx >= T_*B_*F_) return;
  int f = idx % F_, b = (idx / F_) % B_, t = idx / (F_*B_);
  xbf[idx] = f2bf(in[((size_t)b*T_ + t)*F_ + f]);
}

// ---------------- main persistent kernel ----------------
__global__ __launch_bounds__(512, 2) void lstm_main(
    const short* __restrict__ xbf, const short* __restrict__ Wt,
    const short* __restrict__ Wdec, const short* __restrict__ Dwt,
    const float* __restrict__ bvec, const float* __restrict__ bdec,
    const float* __restrict__ dbv, short* hbuf, unsigned* cnt,
    float* __restrict__ out)
{
  __shared__ short wlds[COLSB*LDSTR];   // 149,504 B
  const int tid = threadIdx.x;
  const int bidx = blockIdx.x;
  // group mapping: 16 blocks of a batch-group land on one XCD under round-robin
  const int gb = (bidx & 7)*2 + (bidx >> 7);   // batch group 0..15
  const int gu = (bidx >> 3) & 15;             // unit group 0..15

  // ---- load warm-up weight slice to LDS ----
  {
    const int c = tid >> 2, q = tid & 3;
    const int gate = (c >> 4) & 3;
    const int u = gu*32 + ((c >> 6) << 4) + (c & 15);
    const int gcol = gate*512 + u;
    const short* src = Wt + (size_t)gcol*KTOT + q*144;
    short* dst = wlds + c*LDSTR + q*144;
    #pragma unroll
    for (int j=0;j<18;j++)
      *(bf16x8*)(dst + j*8) = *(const bf16x8*)(src + j*8);
  }
  __syncthreads();

  const int w = tid >> 6, lane = tid & 63;
  const int wm = w >> 1, wn = w & 1;
  const int l15 = lane & 15, kh = lane >> 4;

  const int ucol = gu*32 + wn*16 + l15;        // unit column this lane updates
  float bia[4], biaD[4];
  #pragma unroll
  for (int g=0; g<4; ++g){ bia[g] = bvec[g*512 + ucol]; biaD[g] = bdec[g*512 + ucol]; }

  float cst[2][4] = {};                        // c state (fp32, persistent)
  const int row0 = gb*ROWS + 32*wm + l15;      // a-frag row base (+16*mt)
  unsigned* myCnt = cnt + gb*16;               // 64B-spaced counters

  for (int t=0; t<NSTEP; ++t) {
    const bool warm = (t < T_);
    if (t == T_) {   // swap to folded decode weights (k region 64..575)
      __syncthreads();
      const int c = tid >> 2, q = tid & 3;
      const int gate = (c >> 4) & 3;
      const int u = gu*32 + ((c >> 6) << 4) + (c & 15);
      const int gcol = gate*512 + u;
      const short* src = Wdec + (size_t)gcol*U_ + q*128;
      short* dst = wlds + c*LDSTR + 64 + q*128;
      #pragma unroll
      for (int j=0;j<16;j++)
        *(bf16x8*)(dst + j*8) = *(const bf16x8*)(src + j*8);
      __syncthreads();
    }

    const short* hcur = hbuf + (size_t)(t & 1)*B_*U_;
    short* hnxt = hbuf + (size_t)((t+1) & 1)*B_*U_;

    f32x4 acc[2][4] = {};

    if (warm) {  // x part: K 0..63
      const short* xp = xbf + ((size_t)t*B_ + row0)*F_ + kh*8;
      #pragma unroll
      for (int kx=0; kx<2; ++kx) {
        bf16x8 a0 = *(const bf16x8*)(xp + kx*32);
        bf16x8 a1 = *(const bf16x8*)(xp + 16*F_ + kx*32);
        #pragma unroll
        for (int g=0; g<4; ++g) {
          bf16x8 bf = *(const bf16x8*)(wlds + (64*wn + 16*g + l15)*LDSTR + kx*32 + kh*8);
          acc[0][g] = __builtin_amdgcn_mfma_f32_16x16x32_bf16(a0, bf, acc[0][g], 0,0,0);
          acc[1][g] = __builtin_amdgcn_mfma_f32_16x16x32_bf16(a1, bf, acc[1][g], 0,0,0);
        }
      }
    }
    {  // h part: K 64..575
      const short* hp = hcur + (size_t)row0*U_ + kh*8;
      #pragma unroll
      for (int ks=0; ks<16; ++ks) {
        bf16x8 a0 = *(const bf16x8*)(hp + ks*32);
        bf16x8 a1 = *(const bf16x8*)(hp + 16*U_ + ks*32);
        #pragma unroll
        for (int g=0; g<4; ++g) {
          bf16x8 bf = *(const bf16x8*)(wlds + (64*wn + 16*g + l15)*LDSTR + 64 + ks*32 + kh*8);
          acc[0][g] = __builtin_amdgcn_mfma_f32_16x16x32_bf16(a0, bf, acc[0][g], 0,0,0);
          acc[1][g] = __builtin_amdgcn_mfma_f32_16x16x32_bf16(a1, bf, acc[1][g], 0,0,0);
        }
      }
    }

    // gates + state update + h2 store (C/D layout: col=lane&15, row=kh*4+reg)
    #pragma unroll
    for (int mt=0; mt<2; ++mt) {
      #pragma unroll
      for (int r=0; r<4; ++r) {
        float zi = acc[mt][0][r], zf = acc[mt][1][r], zg = acc[mt][2][r], zo = acc[mt][3][r];
        if (warm) { zi += bia[0];  zf += bia[1];  zg += bia[2];  zo += bia[3]; }
        else      { zi += biaD[0]; zf += biaD[1]; zg += biaD[2]; zo += biaD[3]; }
        float ig = sigm(zi), fg = sigm(zf), gg = tanh_(zg), og = sigm(zo);
        float c2 = fmaf(fg, cst[mt][r], ig*gg);
        cst[mt][r] = c2;
        float h2 = og*tanh_(c2);
        int row = gb*ROWS + 32*wm + 16*mt + kh*4 + r;
        hnxt[(size_t)row*U_ + ucol] = f2bf(h2);
      }
    }

    // ---- intra-group sync (16 blocks) ----
    __syncthreads();                       // drains vmcnt before barrier
    if (tid == 0) {
      __threadfence();                     // agent-scope release (L2 writeback)
      __hip_atomic_fetch_add(myCnt, 1u, __ATOMIC_RELEASE, __HIP_MEMORY_SCOPE_AGENT);
      const unsigned target = 16u*(unsigned)(t+1);
      while (__hip_atomic_load(myCnt, __ATOMIC_ACQUIRE, __HIP_MEMORY_SCOPE_AGENT) < target)
        __builtin_amdgcn_s_sleep(2);
    }
    __syncthreads();

    // ---- pred output (rotating designated block per group) ----
    const int s = t - 127;
    if (s >= 0 && gu == (s & 15)) {
      const short* hb = hbuf + (size_t)((t+1)&1)*B_*U_;
      const int prow = gb*ROWS + 16*w + l15;
      f32x4 pa[4] = {};
      #pragma unroll
      for (int ks=0; ks<16; ++ks) {
        bf16x8 a = *(const bf16x8*)(hb + (size_t)prow*U_ + ks*32 + kh*8);
        #pragma unroll
        for (int n=0; n<4; ++n) {
          bf16x8 bfr = *(const bf16x8*)(Dwt + (size_t)(16*n + l15)*U_ + ks*32 + kh*8);
          pa[n] = __builtin_amdgcn_mfma_f32_16x16x32_bf16(a, bfr, pa[n], 0,0,0);
        }
      }
      #pragma unroll
      for (int n=0; n<4; ++n) {
        int col = 16*n + l15;
        float dbc = dbv[col];
        #pragma unroll
        for (int r=0; r<4; ++r) {
          int orow = gb*ROWS + 16*w + kh*4 + r;
          out[((size_t)orow*OUTS + s)*F_ + col] = pa[n][r] + dbc;
        }
      }
    }
  }
}

extern "C" void kernel_launch(void* const* d_in, const int* in_sizes, int n_in,
                              void* d_out, int out_size, void* d_ws, size_t ws_size,
                              hipStream_t stream) {
  const float* inputs = (const float*)d_in[0];
  const float* Wx = (const float*)d_in[1];
  const float* Wh = (const float*)d_in[2];
  const float* bv = (const float*)d_in[3];
  const float* Dw = (const float*)d_in[4];
  const float* db = (const float*)d_in[5];
  float* out = (float*)d_out;
  char* ws = (char*)d_ws;
  if (ws_size < WS_TOTAL) return;   // fail loudly (output stays poisoned)

  unsigned* cnt = (unsigned*)(ws + OFF_CNT);
  short* hbuf = (short*)(ws + OFF_HBUF);
  short* Wt   = (short*)(ws + OFF_WT);
  short* Wdec = (short*)(ws + OFF_WDEC);
  short* Dwt  = (short*)(ws + OFF_DWT);
  float* bdec = (float*)(ws + OFF_BDEC);
  short* xbf  = (short*)(ws + OFF_XBF);

  // zero sync counters + h0 buffer (every launch -> deterministic)
  hipMemsetAsync(d_ws, 0, OFF_HBUF + (size_t)B_*U_*2, stream);
  prep_wt  <<<(FOURU*KTOT+255)/256, 256, 0, stream>>>(Wx, Wh, Wt);
  prep_wdec<<<(FOURU*U_ +255)/256, 256, 0, stream>>>(Wh, Wx, Dw, Wdec);
  prep_bdec<<<(FOURU     +255)/256, 256, 0, stream>>>(bv, db, Wx, bdec);
  prep_dwt <<<(F_*U_     +255)/256, 256, 0, stream>>>(Dw, Dwt);
  prep_x   <<<(T_*B_*F_  +255)/256, 256, 0, stream>>>(inputs, xbf);
  lstm_main<<<256, 512, 0, stream>>>(xbf, Wt, Wdec, Dwt, bv, bdec, db, hbuf, cnt, out);
}

// Round 2
// 3519.242 us; speedup vs baseline: 1.6480x; 1.6480x over previous
//
#include <hip/hip_runtime.h>
#include <hip/hip_bf16.h>

#define B_ 2048
#define T_ 128
#define F_ 64
#define U_ 512
#define FOURU 2048
#define OUTS 32
#define NSTEP 159
#define ROWS 128      // batch rows per group
#define COLSB 128     // z cols per block (4 gates x 32 units)
#define KTOT 576      // 64 (x) + 512 (h)
#define LDSTR 584     // padded LDS col stride (elements)

typedef __attribute__((ext_vector_type(8))) short bf16x8;
typedef __attribute__((ext_vector_type(4))) float f32x4;

// workspace layout (bytes)
#define OFF_CNT   0
#define OFF_HBUF  4096
#define OFF_WT    (OFF_HBUF + 2*B_*U_*2)
#define OFF_WDEC  (OFF_WT + FOURU*KTOT*2)
#define OFF_DWT   (OFF_WDEC + FOURU*U_*2)
#define OFF_BDEC  (OFF_DWT + F_*U_*2)
#define OFF_XBF   (OFF_BDEC + FOURU*4)
#define WS_TOTAL  (OFF_XBF + (size_t)T_*B_*F_*2)

__device__ __forceinline__ short f2bf(float f) {
  union { float f; unsigned u; } a; a.f = f;
  unsigned u = a.u;
  unsigned r = u + 0x7FFFu + ((u >> 16) & 1u);  // RNE
  return (short)(r >> 16);
}
__device__ __forceinline__ float sigm(float x){ return 1.0f/(1.0f+__expf(-x)); }
__device__ __forceinline__ float tanh_(float x){ return 1.0f - 2.0f/(1.0f+__expf(2.0f*x)); }

// ---------------- prep kernels ----------------
__global__ void prep_wt(const float* __restrict__ Wx, const float* __restrict__ Wh,
                        short* __restrict__ Wt) {
  int idx = blockIdx.x*256 + threadIdx.x;
  if (idx >= FOURU*KTOT) return;
  int c = idx / KTOT, k = idx % KTOT;
  float v = (k < F_) ? Wx[(size_t)k*FOURU + c] : Wh[(size_t)(k-F_)*FOURU + c];
  Wt[idx] = f2bf(v);
}
__global__ void prep_wdec(const float* __restrict__ Wh, const float* __restrict__ Wx,
                          const float* __restrict__ Dw, short* __restrict__ Wdec) {
  int idx = blockIdx.x*256 + threadIdx.x;
  if (idx >= FOURU*U_) return;
  int c = idx / U_, u = idx % U_;
  float a = Wh[(size_t)u*FOURU + c];
  for (int f=0; f<F_; ++f) a += Dw[u*F_ + f] * Wx[(size_t)f*FOURU + c];
  Wdec[idx] = f2bf(a);
}
__global__ void prep_bdec(const float* __restrict__ bv, const float* __restrict__ db,
                          const float* __restrict__ Wx, float* __restrict__ bdec) {
  int c = blockIdx.x*256 + threadIdx.x;
  if (c >= FOURU) return;
  float a = bv[c];
  for (int f=0; f<F_; ++f) a += db[f]*Wx[(size_t)f*FOURU + c];
  bdec[c] = a;
}
__global__ void prep_dwt(const float* __restrict__ Dw, short* __restrict__ Dwt) {
  int idx = blockIdx.x*256 + threadIdx.x;
  if (idx >= F_*U_) return;
  int f = idx / U_, u = idx % U_;
  Dwt[idx] = f2bf(Dw[u*F_ + f]);
}
__global__ void prep_x(const float* __restrict__ in, short* __restrict__ xbf) {
  int idx = blockIdx.x*256 + threadIdx.x;
  if (idx >= T_*B_*F_) return;
  int f = idx % F_, b = (idx / F_) % B_, t = idx / (F_*B_);
  xbf[idx] = f2bf(in[((size_t)b*T_ + t)*F_ + f]);
}

// ---------------- main persistent kernel ----------------
__global__ __launch_bounds__(512, 2) void lstm_main(
    const short* __restrict__ xbf, const short* __restrict__ Wt,
    const short* __restrict__ Wdec, const short* __restrict__ Dwt,
    const float* __restrict__ bvec, const float* __restrict__ bdec,
    const float* __restrict__ dbv, short* hbuf, unsigned* cnt,
    float* __restrict__ out)
{
  __shared__ short wlds[COLSB*LDSTR];   // 149,504 B
  const int tid = threadIdx.x;
  const int bidx = blockIdx.x;
  // group mapping: a group's 16 blocks share (bidx&7) -> same XCD under
  // round-robin dispatch (perf heuristic only; correctness is agent-scope)
  const int gb = (bidx & 7)*2 + (bidx >> 7);   // batch group 0..15
  const int gu = (bidx >> 3) & 15;             // unit group 0..15

  // ---- load warm-up weight slice to LDS ----
  {
    const int c = tid >> 2, q = tid & 3;
    const int gate = (c >> 4) & 3;
    const int u = gu*32 + ((c >> 6) << 4) + (c & 15);
    const int gcol = gate*512 + u;
    const short* src = Wt + (size_t)gcol*KTOT + q*144;
    short* dst = wlds + c*LDSTR + q*144;
    #pragma unroll
    for (int j=0;j<18;j++)
      *(bf16x8*)(dst + j*8) = *(const bf16x8*)(src + j*8);
  }
  __syncthreads();

  const int w = tid >> 6, lane = tid & 63;
  const int wm = w >> 1, wn = w & 1;
  const int l15 = lane & 15, kh = lane >> 4;

  const int ucol = gu*32 + wn*16 + l15;        // unit column this lane updates
  float bia[4], biaD[4];
  #pragma unroll
  for (int g=0; g<4; ++g){ bia[g] = bvec[g*512 + ucol]; biaD[g] = bdec[g*512 + ucol]; }

  float cst[2][4] = {};                        // c state (fp32, persistent)
  const int row0 = gb*ROWS + 32*wm + l15;      // a-frag row base (+16*mt)
  unsigned* myCnt = cnt + gb*16;               // 64B-spaced counters

  for (int t=0; t<NSTEP; ++t) {
    const bool warm = (t < T_);
    if (t == T_) {   // swap to folded decode weights (k region 64..575)
      __syncthreads();
      const int c = tid >> 2, q = tid & 3;
      const int gate = (c >> 4) & 3;
      const int u = gu*32 + ((c >> 6) << 4) + (c & 15);
      const int gcol = gate*512 + u;
      const short* src = Wdec + (size_t)gcol*U_ + q*128;
      short* dst = wlds + c*LDSTR + 64 + q*128;
      #pragma unroll
      for (int j=0;j<16;j++)
        *(bf16x8*)(dst + j*8) = *(const bf16x8*)(src + j*8);
      __syncthreads();
    }

    const short* hcur = hbuf + (size_t)(t & 1)*B_*U_;
    short* hnxt = hbuf + (size_t)((t+1) & 1)*B_*U_;

    f32x4 acc[2][4] = {};

    if (warm) {  // x part: K 0..63
      const short* xp = xbf + ((size_t)t*B_ + row0)*F_ + kh*8;
      #pragma unroll
      for (int kx=0; kx<2; ++kx) {
        bf16x8 a0 = *(const bf16x8*)(xp + kx*32);
        bf16x8 a1 = *(const bf16x8*)(xp + 16*F_ + kx*32);
        #pragma unroll
        for (int g=0; g<4; ++g) {
          bf16x8 bf = *(const bf16x8*)(wlds + (64*wn + 16*g + l15)*LDSTR + kx*32 + kh*8);
          acc[0][g] = __builtin_amdgcn_mfma_f32_16x16x32_bf16(a0, bf, acc[0][g], 0,0,0);
          acc[1][g] = __builtin_amdgcn_mfma_f32_16x16x32_bf16(a1, bf, acc[1][g], 0,0,0);
        }
      }
    }
    {  // h part: K 64..575
      const short* hp = hcur + (size_t)row0*U_ + kh*8;
      #pragma unroll
      for (int ks=0; ks<16; ++ks) {
        bf16x8 a0 = *(const bf16x8*)(hp + ks*32);
        bf16x8 a1 = *(const bf16x8*)(hp + 16*U_ + ks*32);
        #pragma unroll
        for (int g=0; g<4; ++g) {
          bf16x8 bf = *(const bf16x8*)(wlds + (64*wn + 16*g + l15)*LDSTR + 64 + ks*32 + kh*8);
          acc[0][g] = __builtin_amdgcn_mfma_f32_16x16x32_bf16(a0, bf, acc[0][g], 0,0,0);
          acc[1][g] = __builtin_amdgcn_mfma_f32_16x16x32_bf16(a1, bf, acc[1][g], 0,0,0);
        }
      }
    }

    // gates + state update + h2 store (C/D layout: col=lane&15, row=kh*4+reg)
    #pragma unroll
    for (int mt=0; mt<2; ++mt) {
      #pragma unroll
      for (int r=0; r<4; ++r) {
        float zi = acc[mt][0][r], zf = acc[mt][1][r], zg = acc[mt][2][r], zo = acc[mt][3][r];
        if (warm) { zi += bia[0];  zf += bia[1];  zg += bia[2];  zo += bia[3]; }
        else      { zi += biaD[0]; zf += biaD[1]; zg += biaD[2]; zo += biaD[3]; }
        float ig = sigm(zi), fg = sigm(zf), gg = tanh_(zg), og = sigm(zo);
        float c2 = fmaf(fg, cst[mt][r], ig*gg);
        cst[mt][r] = c2;
        float h2 = og*tanh_(c2);
        int row = gb*ROWS + 32*wm + 16*mt + kh*4 + r;
        hnxt[(size_t)row*U_ + ucol] = f2bf(h2);
      }
    }

    // ---- intra-group sync (16 blocks) ----
    // __syncthreads drains each wave's vmcnt -> all h stores are in L2.
    __syncthreads();
    if (tid == 0) {
      // RELEASE: one wbl2 + atomic at coherent point (cross-XCD safe).
      __hip_atomic_fetch_add(myCnt, 1u, __ATOMIC_RELEASE, __HIP_MEMORY_SCOPE_AGENT);
      const unsigned target = 16u*(unsigned)(t+1);
      // Poll with relaxed RMW: executes at the coherent point (always fresh),
      // emits NO cache invalidates (the round-1 ACQUIRE-poll invalidated the
      // XCD L2 every ~128 cycles, chip-wide).
      while (__hip_atomic_fetch_add(myCnt, 0u, __ATOMIC_RELAXED, __HIP_MEMORY_SCOPE_AGENT) < target)
        ;
      // Exactly ONE acquire per step: invalidate L1(+L2) so h reads are fresh.
      __builtin_amdgcn_fence(__ATOMIC_ACQUIRE, "agent");
    }
    __syncthreads();

    // ---- pred output (rotating designated block per group) ----
    const int s = t - 127;
    if (s >= 0 && gu == (s & 15)) {
      const short* hb = hbuf + (size_t)((t+1)&1)*B_*U_;
      const int prow = gb*ROWS + 16*w + l15;
      f32x4 pa[4] = {};
      #pragma unroll
      for (int ks=0; ks<16; ++ks) {
        bf16x8 a = *(const bf16x8*)(hb + (size_t)prow*U_ + ks*32 + kh*8);
        #pragma unroll
        for (int n=0; n<4; ++n) {
          bf16x8 bfr = *(const bf16x8*)(Dwt + (size_t)(16*n + l15)*U_ + ks*32 + kh*8);
          pa[n] = __builtin_amdgcn_mfma_f32_16x16x32_bf16(a, bfr, pa[n], 0,0,0);
        }
      }
      #pragma unroll
      for (int n=0; n<4; ++n) {
        int col = 16*n + l15;
        float dbc = dbv[col];
        #pragma unroll
        for (int r=0; r<4; ++r) {
          int orow = gb*ROWS + 16*w + kh*4 + r;
          out[((size_t)orow*OUTS + s)*F_ + col] = pa[n][r] + dbc;
        }
      }
    }
  }
}

extern "C" void kernel_launch(void* const* d_in, const int* in_sizes, int n_in,
                              void* d_out, int out_size, void* d_ws, size_t ws_size,
                              hipStream_t stream) {
  const float* inputs = (const float*)d_in[0];
  const float* Wx = (const float*)d_in[1];
  const float* Wh = (const float*)d_in[2];
  const float* bv = (const float*)d_in[3];
  const float* Dw = (const float*)d_in[4];
  const float* db = (const float*)d_in[5];
  float* out = (float*)d_out;
  char* ws = (char*)d_ws;
  if (ws_size < WS_TOTAL) return;   // fail loudly (output stays poisoned)

  unsigned* cnt = (unsigned*)(ws + OFF_CNT);
  short* hbuf = (short*)(ws + OFF_HBUF);
  short* Wt   = (short*)(ws + OFF_WT);
  short* Wdec = (short*)(ws + OFF_WDEC);
  short* Dwt  = (short*)(ws + OFF_DWT);
  float* bdec = (float*)(ws + OFF_BDEC);
  short* xbf  = (short*)(ws + OFF_XBF);

  // zero sync counters + h0 buffer (every launch -> deterministic)
  hipMemsetAsync(d_ws, 0, OFF_HBUF + (size_t)B_*U_*2, stream);
  prep_wt  <<<(FOURU*KTOT+255)/256, 256, 0, stream>>>(Wx, Wh, Wt);
  prep_wdec<<<(FOURU*U_ +255)/256, 256, 0, stream>>>(Wh, Wx, Dw, Wdec);
  prep_bdec<<<(FOURU     +255)/256, 256, 0, stream>>>(bv, db, Wx, bdec);
  prep_dwt <<<(F_*U_     +255)/256, 256, 0, stream>>>(Dw, Dwt);
  prep_x   <<<(T_*B_*F_  +255)/256, 256, 0, stream>>>(inputs, xbf);
  lstm_main<<<256, 512, 0, stream>>>(xbf, Wt, Wdec, Dwt, bv, bdec, db, hbuf, cnt, out);
}

// Round 3
// 2492.304 us; speedup vs baseline: 2.3271x; 1.4120x over previous
//
#include <hip/hip_runtime.h>
#include <hip/hip_bf16.h>

#define B_ 2048
#define T_ 128
#define F_ 64
#define U_ 512
#define FOURU 2048
#define OUTS 32
#define NSTEP 159
#define ROWS 128      // batch rows per group
#define COLSB 128     // z cols per block (4 gates x 32 units)
#define KTOT 576      // 64 (x) + 512 (h)
#define LDSTR 584     // padded LDS col stride (elements)

typedef __attribute__((ext_vector_type(8))) short bf16x8;
typedef __attribute__((ext_vector_type(4))) float f32x4;

// workspace layout (bytes). First 4096 B zeroed every launch:
//   [0..1023]    step counters   (16 groups x 64B spacing)
//   [1024..2047] regist counters (16 groups x 64B spacing)
//   [2048..3071] xcd table       (16 groups x 16 x 4B)
#define OFF_CNT   0
#define OFF_HBUF  4096
#define OFF_WT    (OFF_HBUF + 2*B_*U_*2)
#define OFF_WDEC  (OFF_WT + FOURU*KTOT*2)
#define OFF_DWT   (OFF_WDEC + FOURU*U_*2)
#define OFF_BDEC  (OFF_DWT + F_*U_*2)
#define OFF_XBF   (OFF_BDEC + FOURU*4)
#define WS_TOTAL  (OFF_XBF + (size_t)T_*B_*F_*2)

__device__ __forceinline__ short f2bf(float f) {
  union { float f; unsigned u; } a; a.f = f;
  unsigned u = a.u;
  unsigned r = u + 0x7FFFu + ((u >> 16) & 1u);  // RNE
  return (short)(r >> 16);
}
__device__ __forceinline__ float sigm(float x){ return 1.0f/(1.0f+__expf(-x)); }
__device__ __forceinline__ float tanh_(float x){ return 1.0f - 2.0f/(1.0f+__expf(2.0f*x)); }

// ---------------- prep kernels ----------------
__global__ void prep_wt(const float* __restrict__ Wx, const float* __restrict__ Wh,
                        short* __restrict__ Wt) {
  int idx = blockIdx.x*256 + threadIdx.x;
  if (idx >= FOURU*KTOT) return;
  int c = idx / KTOT, k = idx % KTOT;
  float v = (k < F_) ? Wx[(size_t)k*FOURU + c] : Wh[(size_t)(k-F_)*FOURU + c];
  Wt[idx] = f2bf(v);
}
__global__ void prep_wdec(const float* __restrict__ Wh, const float* __restrict__ Wx,
                          const float* __restrict__ Dw, short* __restrict__ Wdec) {
  int idx = blockIdx.x*256 + threadIdx.x;
  if (idx >= FOURU*U_) return;
  int c = idx / U_, u = idx % U_;
  float a = Wh[(size_t)u*FOURU + c];
  for (int f=0; f<F_; ++f) a += Dw[u*F_ + f] * Wx[(size_t)f*FOURU + c];
  Wdec[idx] = f2bf(a);
}
__global__ void prep_bdec(const float* __restrict__ bv, const float* __restrict__ db,
                          const float* __restrict__ Wx, float* __restrict__ bdec) {
  int c = blockIdx.x*256 + threadIdx.x;
  if (c >= FOURU) return;
  float a = bv[c];
  for (int f=0; f<F_; ++f) a += db[f]*Wx[(size_t)f*FOURU + c];
  bdec[c] = a;
}
__global__ void prep_dwt(const float* __restrict__ Dw, short* __restrict__ Dwt) {
  int idx = blockIdx.x*256 + threadIdx.x;
  if (idx >= F_*U_) return;
  int f = idx / U_, u = idx % U_;
  Dwt[idx] = f2bf(Dw[u*F_ + f]);
}
__global__ void prep_x(const float* __restrict__ in, short* __restrict__ xbf) {
  int idx = blockIdx.x*256 + threadIdx.x;
  if (idx >= T_*B_*F_) return;
  int f = idx % F_, b = (idx / F_) % B_, t = idx / (F_*B_);
  xbf[idx] = f2bf(in[((size_t)b*T_ + t)*F_ + f]);
}

// ---------------- main persistent kernel ----------------
__global__ __launch_bounds__(512, 2) void lstm_main(
    const short* __restrict__ xbf, const short* __restrict__ Wt,
    const short* __restrict__ Wdec, const short* __restrict__ Dwt,
    const float* __restrict__ bvec, const float* __restrict__ bdec,
    const float* __restrict__ dbv, short* hbuf, unsigned* cnt,
    float* __restrict__ out)
{
  __shared__ short wlds[COLSB*LDSTR];   // 149,504 B
  __shared__ int sSame;
  const int tid = threadIdx.x;
  const int bidx = blockIdx.x;
  // group mapping: a group's 16 blocks share bidx%8 -> same XCD under
  // round-robin dispatch (perf heuristic; VERIFIED at runtime below)
  const int gb = (bidx & 7)*2 + (bidx >> 7);   // batch group 0..15
  const int gu = (bidx >> 3) & 15;             // unit group 0..15

  unsigned* stepCnt = cnt + gb*16;             // 64B-spaced
  unsigned* regCnt  = cnt + 256 + gb*16;       // 64B-spaced
  unsigned* xcdTab  = cnt + 512 + gb*16;       // 16 entries

  // ---- runtime XCD-uniformity check for this group ----
  {
    unsigned xcc;
    asm volatile("s_getreg_b32 %0, hwreg(HW_REG_XCC_ID)" : "=s"(xcc));
    if (tid == 0) {
      __hip_atomic_store(&xcdTab[gu], xcc + 1u, __ATOMIC_RELAXED, __HIP_MEMORY_SCOPE_AGENT);
      __hip_atomic_fetch_add(regCnt, 1u, __ATOMIC_RELEASE, __HIP_MEMORY_SCOPE_AGENT);
      while (__hip_atomic_fetch_add(regCnt, 0u, __ATOMIC_RELAXED, __HIP_MEMORY_SCOPE_AGENT) < 16u)
        __builtin_amdgcn_s_sleep(1);
      __builtin_amdgcn_fence(__ATOMIC_ACQUIRE, "agent");
      unsigned x0 = __hip_atomic_load(&xcdTab[0], __ATOMIC_RELAXED, __HIP_MEMORY_SCOPE_AGENT);
      int same = 1;
      for (int i = 1; i < 16; ++i)
        same &= (__hip_atomic_load(&xcdTab[i], __ATOMIC_RELAXED, __HIP_MEMORY_SCOPE_AGENT) == x0);
      sSame = same;
    }
  }

  // ---- load warm-up weight slice to LDS ----
  {
    const int c = tid >> 2, q = tid & 3;
    const int gate = (c >> 4) & 3;
    const int u = gu*32 + ((c >> 6) << 4) + (c & 15);
    const int gcol = gate*512 + u;
    const short* src = Wt + (size_t)gcol*KTOT + q*144;
    short* dst = wlds + c*LDSTR + q*144;
    #pragma unroll
    for (int j=0;j<18;j++)
      *(bf16x8*)(dst + j*8) = *(const bf16x8*)(src + j*8);
  }
  __syncthreads();
  const bool fastSync = (sSame != 0);   // uniform across block

  const int w = tid >> 6, lane = tid & 63;
  const int wm = w >> 1, wn = w & 1;
  const int l15 = lane & 15, kh = lane >> 4;

  const int ucol = gu*32 + wn*16 + l15;        // unit column this lane updates
  float bia[4], biaD[4];
  #pragma unroll
  for (int g=0; g<4; ++g){ bia[g] = bvec[g*512 + ucol]; biaD[g] = bdec[g*512 + ucol]; }

  float cst[2][4] = {};                        // c state (fp32, persistent)
  const int row0 = gb*ROWS + 32*wm + l15;      // a-frag row base (+16*mt)

  for (int t=0; t<NSTEP; ++t) {
    const bool warm = (t < T_);
    if (t == T_) {   // swap to folded decode weights (k region 64..575)
      __syncthreads();
      const int c = tid >> 2, q = tid & 3;
      const int gate = (c >> 4) & 3;
      const int u = gu*32 + ((c >> 6) << 4) + (c & 15);
      const int gcol = gate*512 + u;
      const short* src = Wdec + (size_t)gcol*U_ + q*128;
      short* dst = wlds + c*LDSTR + 64 + q*128;
      #pragma unroll
      for (int j=0;j<16;j++)
        *(bf16x8*)(dst + j*8) = *(const bf16x8*)(src + j*8);
      __syncthreads();
    }

    const short* hcur = hbuf + (size_t)(t & 1)*B_*U_;
    short* hnxt = hbuf + (size_t)((t+1) & 1)*B_*U_;

    f32x4 acc[2][4] = {};

    if (warm) {  // x part: K 0..63
      const short* xp = xbf + ((size_t)t*B_ + row0)*F_ + kh*8;
      #pragma unroll
      for (int kx=0; kx<2; ++kx) {
        bf16x8 a0 = *(const bf16x8*)(xp + kx*32);
        bf16x8 a1 = *(const bf16x8*)(xp + 16*F_ + kx*32);
        #pragma unroll
        for (int g=0; g<4; ++g) {
          bf16x8 bf = *(const bf16x8*)(wlds + (64*wn + 16*g + l15)*LDSTR + kx*32 + kh*8);
          acc[0][g] = __builtin_amdgcn_mfma_f32_16x16x32_bf16(a0, bf, acc[0][g], 0,0,0);
          acc[1][g] = __builtin_amdgcn_mfma_f32_16x16x32_bf16(a1, bf, acc[1][g], 0,0,0);
        }
      }
    }
    {  // h part: K 64..575
      const short* hp = hcur + (size_t)row0*U_ + kh*8;
      #pragma unroll
      for (int ks=0; ks<16; ++ks) {
        bf16x8 a0 = *(const bf16x8*)(hp + ks*32);
        bf16x8 a1 = *(const bf16x8*)(hp + 16*U_ + ks*32);
        #pragma unroll
        for (int g=0; g<4; ++g) {
          bf16x8 bf = *(const bf16x8*)(wlds + (64*wn + 16*g + l15)*LDSTR + 64 + ks*32 + kh*8);
          acc[0][g] = __builtin_amdgcn_mfma_f32_16x16x32_bf16(a0, bf, acc[0][g], 0,0,0);
          acc[1][g] = __builtin_amdgcn_mfma_f32_16x16x32_bf16(a1, bf, acc[1][g], 0,0,0);
        }
      }
    }

    // gates + state update + h2 store (C/D layout: col=lane&15, row=kh*4+reg)
    #pragma unroll
    for (int mt=0; mt<2; ++mt) {
      #pragma unroll
      for (int r=0; r<4; ++r) {
        float zi = acc[mt][0][r], zf = acc[mt][1][r], zg = acc[mt][2][r], zo = acc[mt][3][r];
        if (warm) { zi += bia[0];  zf += bia[1];  zg += bia[2];  zo += bia[3]; }
        else      { zi += biaD[0]; zf += biaD[1]; zg += biaD[2]; zo += biaD[3]; }
        float ig = sigm(zi), fg = sigm(zf), gg = tanh_(zg), og = sigm(zo);
        float c2 = fmaf(fg, cst[mt][r], ig*gg);
        cst[mt][r] = c2;
        float h2 = og*tanh_(c2);
        int row = gb*ROWS + 32*wm + 16*mt + kh*4 + r;
        hnxt[(size_t)row*U_ + ucol] = f2bf(h2);
      }
    }

    // ---- intra-group sync (16 blocks) ----
    // __syncthreads drains vmcnt -> all h stores are committed to XCD L2.
    __syncthreads();
    if (tid == 0) {
      const unsigned target = 16u*(unsigned)(t+1);
      if (fastSync) {
        // Same-XCD path: L2 is one physical cache for the whole group.
        // No wbl2, no L2 invalidate. RMW counter at coherent point for
        // freshness; reader only invalidates its CU's L1.
        __hip_atomic_fetch_add(stepCnt, 1u, __ATOMIC_RELAXED, __HIP_MEMORY_SCOPE_AGENT);
        while (__hip_atomic_fetch_add(stepCnt, 0u, __ATOMIC_RELAXED, __HIP_MEMORY_SCOPE_AGENT) < target)
          __builtin_amdgcn_s_sleep(1);
        asm volatile("buffer_inv sc0" ::: "memory");        // L1 invalidate
        asm volatile("s_waitcnt vmcnt(0)" ::: "memory");
      } else {
        // Cross-XCD fallback: full release/acquire (round-2 behavior).
        __hip_atomic_fetch_add(stepCnt, 1u, __ATOMIC_RELEASE, __HIP_MEMORY_SCOPE_AGENT);
        while (__hip_atomic_fetch_add(stepCnt, 0u, __ATOMIC_RELAXED, __HIP_MEMORY_SCOPE_AGENT) < target)
          __builtin_amdgcn_s_sleep(1);
        __builtin_amdgcn_fence(__ATOMIC_ACQUIRE, "agent");
      }
    }
    __syncthreads();

    // ---- pred output (rotating designated block per group) ----
    const int s = t - 127;
    if (s >= 0 && gu == (s & 15)) {
      const short* hb = hbuf + (size_t)((t+1)&1)*B_*U_;
      const int prow = gb*ROWS + 16*w + l15;
      f32x4 pa[4] = {};
      #pragma unroll
      for (int ks=0; ks<16; ++ks) {
        bf16x8 a = *(const bf16x8*)(hb + (size_t)prow*U_ + ks*32 + kh*8);
        #pragma unroll
        for (int n=0; n<4; ++n) {
          bf16x8 bfr = *(const bf16x8*)(Dwt + (size_t)(16*n + l15)*U_ + ks*32 + kh*8);
          pa[n] = __builtin_amdgcn_mfma_f32_16x16x32_bf16(a, bfr, pa[n], 0,0,0);
        }
      }
      #pragma unroll
      for (int n=0; n<4; ++n) {
        int col = 16*n + l15;
        float dbc = dbv[col];
        #pragma unroll
        for (int r=0; r<4; ++r) {
          int orow = gb*ROWS + 16*w + kh*4 + r;
          out[((size_t)orow*OUTS + s)*F_ + col] = pa[n][r] + dbc;
        }
      }
    }
  }
}

extern "C" void kernel_launch(void* const* d_in, const int* in_sizes, int n_in,
                              void* d_out, int out_size, void* d_ws, size_t ws_size,
                              hipStream_t stream) {
  const float* inputs = (const float*)d_in[0];
  const float* Wx = (const float*)d_in[1];
  const float* Wh = (const float*)d_in[2];
  const float* bv = (const float*)d_in[3];
  const float* Dw = (const float*)d_in[4];
  const float* db = (const float*)d_in[5];
  float* out = (float*)d_out;
  char* ws = (char*)d_ws;
  if (ws_size < WS_TOTAL) return;   // fail loudly (output stays poisoned)

  unsigned* cnt = (unsigned*)(ws + OFF_CNT);
  short* hbuf = (short*)(ws + OFF_HBUF);
  short* Wt   = (short*)(ws + OFF_WT);
  short* Wdec = (short*)(ws + OFF_WDEC);
  short* Dwt  = (short*)(ws + OFF_DWT);
  float* bdec = (float*)(ws + OFF_BDEC);
  short* xbf  = (short*)(ws + OFF_XBF);

  // zero sync counters + h0 buffer (every launch -> deterministic)
  hipMemsetAsync(d_ws, 0, OFF_HBUF + (size_t)B_*U_*2, stream);
  prep_wt  <<<(FOURU*KTOT+255)/256, 256, 0, stream>>>(Wx, Wh, Wt);
  prep_wdec<<<(FOURU*U_ +255)/256, 256, 0, stream>>>(Wh, Wx, Dw, Wdec);
  prep_bdec<<<(FOURU     +255)/256, 256, 0, stream>>>(bv, db, Wx, bdec);
  prep_dwt <<<(F_*U_     +255)/256, 256, 0, stream>>>(Dw, Dwt);
  prep_x   <<<(T_*B_*F_  +255)/256, 256, 0, stream>>>(inputs, xbf);
  lstm_main<<<256, 512, 0, stream>>>(xbf, Wt, Wdec, Dwt, bv, bdec, db, hbuf, cnt, out);
}

// Round 4
// 1811.543 us; speedup vs baseline: 3.2016x; 1.3758x over previous
//
#include <hip/hip_runtime.h>
#include <hip/hip_bf16.h>

#define B_ 2048
#define T_ 128
#define F_ 64
#define U_ 512
#define FOURU 2048
#define OUTS 32
#define ROWS 128      // batch rows per group
#define COLSB 128     // z cols per block (4 gates x 32 units)
#define KTOT 576      // 64 (x) + 512 (h)
#define LDSTR 584     // padded LDS col stride (elements)

typedef __attribute__((ext_vector_type(8))) short bf16x8;
typedef __attribute__((ext_vector_type(4))) float f32x4;

// workspace layout (bytes). First 20480 B zeroed every launch:
//   dw [0..4095]      flags: group gb, block gu at dw gb*256+gu*16 (64B spaced)
//   dw [4096..4351]   regist counters (16 groups x 16dw)
//   dw [4352..4607]   xcd table (16 groups x 16dw)
//   dw [4608..4863]   fallback step counters (16 groups x 16dw)
#define OFF_CNT   0
#define OFF_HBUF  20480
#define OFF_WT    (OFF_HBUF + 2*B_*U_*2)
#define OFF_WDEC  (OFF_WT + FOURU*KTOT*2)
#define OFF_DWT   (OFF_WDEC + FOURU*U_*2)
#define OFF_BDEC  (OFF_DWT + F_*U_*2)
#define OFF_XBF   (OFF_BDEC + FOURU*4)
#define WS_TOTAL  (OFF_XBF + (size_t)T_*B_*F_*2)

__device__ __forceinline__ short f2bf(float f) {
  union { float f; unsigned u; } a; a.f = f;
  unsigned u = a.u;
  unsigned r = u + 0x7FFFu + ((u >> 16) & 1u);  // RNE
  return (short)(r >> 16);
}
__device__ __forceinline__ float sigm(float x){ return 1.0f/(1.0f+__expf(-x)); }
__device__ __forceinline__ float tanh_(float x){ return 1.0f - 2.0f/(1.0f+__expf(2.0f*x)); }

// ---------------- prep kernels ----------------
__global__ void prep_wt(const float* __restrict__ Wx, const float* __restrict__ Wh,
                        short* __restrict__ Wt) {
  int idx = blockIdx.x*256 + threadIdx.x;
  if (idx >= FOURU*KTOT) return;
  int c = idx / KTOT, k = idx % KTOT;
  float v = (k < F_) ? Wx[(size_t)k*FOURU + c] : Wh[(size_t)(k-F_)*FOURU + c];
  Wt[idx] = f2bf(v);
}
__global__ void prep_wdec(const float* __restrict__ Wh, const float* __restrict__ Wx,
                          const float* __restrict__ Dw, short* __restrict__ Wdec) {
  int idx = blockIdx.x*256 + threadIdx.x;
  if (idx >= FOURU*U_) return;
  int c = idx / U_, u = idx % U_;
  float a = Wh[(size_t)u*FOURU + c];
  for (int f=0; f<F_; ++f) a += Dw[u*F_ + f] * Wx[(size_t)f*FOURU + c];
  Wdec[idx] = f2bf(a);
}
__global__ void prep_bdec(const float* __restrict__ bv, const float* __restrict__ db,
                          const float* __restrict__ Wx, float* __restrict__ bdec) {
  int c = blockIdx.x*256 + threadIdx.x;
  if (c >= FOURU) return;
  float a = bv[c];
  for (int f=0; f<F_; ++f) a += db[f]*Wx[(size_t)f*FOURU + c];
  bdec[c] = a;
}
__global__ void prep_dwt(const float* __restrict__ Dw, short* __restrict__ Dwt) {
  int idx = blockIdx.x*256 + threadIdx.x;
  if (idx >= F_*U_) return;
  int f = idx / U_, u = idx % U_;
  Dwt[idx] = f2bf(Dw[u*F_ + f]);
}
__global__ void prep_x(const float* __restrict__ in, short* __restrict__ xbf) {
  int idx = blockIdx.x*256 + threadIdx.x;
  if (idx >= T_*B_*F_) return;
  int f = idx % F_, b = (idx / F_) % B_, t = idx / (F_*B_);
  xbf[idx] = f2bf(in[((size_t)b*T_ + t)*F_ + f]);
}

// ---------------- main persistent kernel ----------------
// 1024 threads = 16 waves; 1 block/CU (LDS-bound) -> 4 waves/SIMD.
__global__ __launch_bounds__(1024, 4) void lstm_main(
    const short* __restrict__ xbf, const short* __restrict__ Wt,
    const short* __restrict__ Wdec, const short* __restrict__ Dwt,
    const float* __restrict__ bvec, const float* __restrict__ bdec,
    const float* __restrict__ dbv, short* hbuf, unsigned* cnt,
    float* __restrict__ out)
{
  __shared__ short wlds[COLSB*LDSTR];   // 149,504 B
  __shared__ int sSame;
  const int tid = threadIdx.x;
  const int bidx = blockIdx.x;
  // a group's 16 blocks share bidx%8 -> same XCD under round-robin dispatch
  // (perf heuristic; verified at runtime below, fallback is cross-XCD safe)
  const int gb = (bidx & 7)*2 + (bidx >> 7);   // batch group 0..15
  const int gu = (bidx >> 3) & 15;             // unit group 0..15

  unsigned* flags   = cnt + gb*256;            // 16 flags, 64B spaced
  unsigned* myFlag  = flags + gu*16;
  unsigned* regCnt  = cnt + 4096 + gb*16;
  unsigned* xcdTab  = cnt + 4352 + gb*16;
  unsigned* stepCnt = cnt + 4608 + gb*16;

  // ---- runtime XCD-uniformity check for this group ----
  {
    unsigned xcc;
    asm volatile("s_getreg_b32 %0, hwreg(HW_REG_XCC_ID)" : "=s"(xcc));
    if (tid == 0) {
      __hip_atomic_store(&xcdTab[gu], xcc + 1u, __ATOMIC_RELAXED, __HIP_MEMORY_SCOPE_AGENT);
      __hip_atomic_fetch_add(regCnt, 1u, __ATOMIC_RELEASE, __HIP_MEMORY_SCOPE_AGENT);
      while (__hip_atomic_fetch_add(regCnt, 0u, __ATOMIC_RELAXED, __HIP_MEMORY_SCOPE_AGENT) < 16u)
        __builtin_amdgcn_s_sleep(1);
      __builtin_amdgcn_fence(__ATOMIC_ACQUIRE, "agent");
      unsigned x0 = __hip_atomic_load(&xcdTab[0], __ATOMIC_RELAXED, __HIP_MEMORY_SCOPE_AGENT);
      int same = 1;
      for (int i = 1; i < 16; ++i)
        same &= (__hip_atomic_load(&xcdTab[i], __ATOMIC_RELAXED, __HIP_MEMORY_SCOPE_AGENT) == x0);
      sSame = same;
    }
  }

  // ---- load warm-up weight slice to LDS (1024 threads: col=tid>>3, 72 B each) ----
  {
    const int c = tid >> 3, q = tid & 7;
    const int gate = (c >> 4) & 3;
    const int u = gu*32 + ((c >> 6) << 4) + (c & 15);
    const int gcol = gate*512 + u;
    const short* src = Wt + (size_t)gcol*KTOT + q*72;
    short* dst = wlds + c*LDSTR + q*72;
    #pragma unroll
    for (int j=0;j<9;j++)
      *(bf16x8*)(dst + j*8) = *(const bf16x8*)(src + j*8);
  }
  __syncthreads();
  const bool fastSync = (sSame != 0);

  const int w = tid >> 6, lane = tid & 63;
  const int wm = w >> 1, wn = w & 1;           // 8 row-groups x 2 col-halves
  const int l15 = lane & 15, kh = lane >> 4;

  const int ucol = gu*32 + wn*16 + l15;        // unit column this lane updates
  float bia[4], biaD[4];
  #pragma unroll
  for (int g=0; g<4; ++g){ bia[g] = bvec[g*512 + ucol]; biaD[g] = bdec[g*512 + ucol]; }

  float cst[4] = {};                           // c state (fp32, persistent)
  const int rowA = gb*ROWS + wm*16 + l15;      // A-frag row for this lane

  f32x4 acc[4];
  // prologue: x-part for t=0 (h(0)=0 so h-part of iter 0 adds zeros)
  {
    const short* xp = xbf + ((size_t)0*B_ + rowA)*F_ + kh*8;
    bf16x8 a0 = *(const bf16x8*)(xp);
    bf16x8 a1 = *(const bf16x8*)(xp + 32);
    #pragma unroll
    for (int g=0; g<4; ++g) {
      bf16x8 b0 = *(const bf16x8*)(wlds + (size_t)(wn*64 + 16*g + l15)*LDSTR + kh*8);
      bf16x8 b1 = *(const bf16x8*)(wlds + (size_t)(wn*64 + 16*g + l15)*LDSTR + 32 + kh*8);
      f32x4 z = {0.f,0.f,0.f,0.f};
      z = __builtin_amdgcn_mfma_f32_16x16x32_bf16(a0, b0, z, 0,0,0);
      acc[g] = __builtin_amdgcn_mfma_f32_16x16x32_bf16(a1, b1, z, 0,0,0);
    }
  }

  for (int t = 0; t < 160; ++t) {
    // ---- wait: all 16 group flags >= t ----
    if (t > 0) {
      if (fastSync) {
        if (tid < 64) {
          unsigned* fl = flags + (tid & 15)*16;
          for (;;) {
            unsigned v = __hip_atomic_load(fl, __ATOMIC_RELAXED, __HIP_MEMORY_SCOPE_AGENT);
            if (__ballot(v >= (unsigned)t) == ~0ull) break;
            __builtin_amdgcn_s_sleep(1);
          }
          asm volatile("buffer_inv sc0" ::: "memory");     // L1 invalidate
          asm volatile("s_waitcnt vmcnt(0)" ::: "memory");
        }
      } else {
        if (tid == 0) {
          const unsigned target = 16u*(unsigned)t;
          while (__hip_atomic_fetch_add(stepCnt, 0u, __ATOMIC_RELAXED, __HIP_MEMORY_SCOPE_AGENT) < target)
            __builtin_amdgcn_s_sleep(1);
          __builtin_amdgcn_fence(__ATOMIC_ACQUIRE, "agent");
        }
      }
      __syncthreads();
    }

    // ---- pred s = t-128 (distributed: blocks gu<8, 16 rows each, waves 0-3) ----
    if (t >= 128) {
      const int s = t - 128;
      if (gu < 8 && w < 4) {
        const short* hb = hbuf + (size_t)(t & 1)*B_*U_;
        const int pr0 = gb*ROWS + gu*16 + l15;
        f32x4 pa = {0.f,0.f,0.f,0.f};
        #pragma unroll
        for (int ks=0; ks<16; ++ks) {
          bf16x8 a = *(const bf16x8*)(hb + (size_t)pr0*U_ + ks*32 + kh*8);
          bf16x8 b = *(const bf16x8*)(Dwt + (size_t)(w*16 + l15)*U_ + ks*32 + kh*8);
          pa = __builtin_amdgcn_mfma_f32_16x16x32_bf16(a, b, pa, 0,0,0);
        }
        const int col = w*16 + l15;
        const float dbc = dbv[col];
        #pragma unroll
        for (int r=0; r<4; ++r) {
          const int orow = gb*ROWS + gu*16 + kh*4 + r;
          out[((size_t)orow*OUTS + s)*F_ + col] = pa[r] + dbc;
        }
      }
    }
    if (t == 159) break;
    if (t == 128) {   // swap to folded decode weights (k region 64..575)
      __syncthreads();
      const int c = tid >> 3, q = tid & 7;
      const int gate = (c >> 4) & 3;
      const int u = gu*32 + ((c >> 6) << 4) + (c & 15);
      const int gcol = gate*512 + u;
      const short* src = Wdec + (size_t)gcol*U_ + q*64;
      short* dst = wlds + c*LDSTR + 64 + q*64;
      #pragma unroll
      for (int j=0;j<8;j++)
        *(bf16x8*)(dst + j*8) = *(const bf16x8*)(src + j*8);
      __syncthreads();
    }

    // ---- h-part: K 64..575 ----
    const short* hcur = hbuf + (size_t)(t & 1)*B_*U_;
    short* hnxt = hbuf + (size_t)((t+1) & 1)*B_*U_;
    {
      const short* hp = hcur + (size_t)rowA*U_ + kh*8;
      #pragma unroll
      for (int ks=0; ks<16; ++ks) {
        bf16x8 a = *(const bf16x8*)(hp + ks*32);
        #pragma unroll
        for (int g=0; g<4; ++g) {
          bf16x8 b = *(const bf16x8*)(wlds + (size_t)(wn*64 + 16*g + l15)*LDSTR + 64 + ks*32 + kh*8);
          acc[g] = __builtin_amdgcn_mfma_f32_16x16x32_bf16(a, b, acc[g], 0,0,0);
        }
      }
    }

    // ---- gates + state update + h2 store (C/D: col=l15, row=kh*4+r) ----
    {
      const bool warm = (t < T_);
      #pragma unroll
      for (int r=0; r<4; ++r) {
        float zi = acc[0][r] + (warm ? bia[0] : biaD[0]);
        float zf = acc[1][r] + (warm ? bia[1] : biaD[1]);
        float zg = acc[2][r] + (warm ? bia[2] : biaD[2]);
        float zo = acc[3][r] + (warm ? bia[3] : biaD[3]);
        float ig = sigm(zi), fg = sigm(zf), gg = tanh_(zg), og = sigm(zo);
        float c2 = fmaf(fg, cst[r], ig*gg);
        cst[r] = c2;
        float h2 = og*tanh_(c2);
        const int row = gb*ROWS + wm*16 + kh*4 + r;
        hnxt[(size_t)row*U_ + ucol] = f2bf(h2);
      }
    }

    // ---- release: drain stores, set own flag ----
    __syncthreads();                       // drains vmcnt -> h in L2
    if (tid == 0) {
      if (fastSync)
        __hip_atomic_store(myFlag, (unsigned)(t+1), __ATOMIC_RELAXED, __HIP_MEMORY_SCOPE_AGENT);
      else
        __hip_atomic_fetch_add(stepCnt, 1u, __ATOMIC_RELEASE, __HIP_MEMORY_SCOPE_AGENT);
    }

    // ---- x-part for t+1 (group-independent; shadows barrier latency) ----
    if (t + 1 < T_) {
      const short* xp = xbf + ((size_t)(t+1)*B_ + rowA)*F_ + kh*8;
      bf16x8 a0 = *(const bf16x8*)(xp);
      bf16x8 a1 = *(const bf16x8*)(xp + 32);
      #pragma unroll
      for (int g=0; g<4; ++g) {
        bf16x8 b0 = *(const bf16x8*)(wlds + (size_t)(wn*64 + 16*g + l15)*LDSTR + kh*8);
        bf16x8 b1 = *(const bf16x8*)(wlds + (size_t)(wn*64 + 16*g + l15)*LDSTR + 32 + kh*8);
        f32x4 z = {0.f,0.f,0.f,0.f};
        z = __builtin_amdgcn_mfma_f32_16x16x32_bf16(a0, b0, z, 0,0,0);
        acc[g] = __builtin_amdgcn_mfma_f32_16x16x32_bf16(a1, b1, z, 0,0,0);
      }
    } else {
      #pragma unroll
      for (int g=0; g<4; ++g) acc[g] = (f32x4){0.f,0.f,0.f,0.f};
    }
  }
}

extern "C" void kernel_launch(void* const* d_in, const int* in_sizes, int n_in,
                              void* d_out, int out_size, void* d_ws, size_t ws_size,
                              hipStream_t stream) {
  const float* inputs = (const float*)d_in[0];
  const float* Wx = (const float*)d_in[1];
  const float* Wh = (const float*)d_in[2];
  const float* bv = (const float*)d_in[3];
  const float* Dw = (const float*)d_in[4];
  const float* db = (const float*)d_in[5];
  float* out = (float*)d_out;
  char* ws = (char*)d_ws;
  if (ws_size < WS_TOTAL) return;   // fail loudly (output stays poisoned)

  unsigned* cnt = (unsigned*)(ws + OFF_CNT);
  short* hbuf = (short*)(ws + OFF_HBUF);
  short* Wt   = (short*)(ws + OFF_WT);
  short* Wdec = (short*)(ws + OFF_WDEC);
  short* Dwt  = (short*)(ws + OFF_DWT);
  float* bdec = (float*)(ws + OFF_BDEC);
  short* xbf  = (short*)(ws + OFF_XBF);

  // zero sync area + h0 buffer (every launch -> deterministic)
  hipMemsetAsync(d_ws, 0, OFF_HBUF + (size_t)B_*U_*2, stream);
  prep_wt  <<<(FOURU*KTOT+255)/256, 256, 0, stream>>>(Wx, Wh, Wt);
  prep_wdec<<<(FOURU*U_ +255)/256, 256, 0, stream>>>(Wh, Wx, Dw, Wdec);
  prep_bdec<<<(FOURU     +255)/256, 256, 0, stream>>>(bv, db, Wx, bdec);
  prep_dwt <<<(F_*U_     +255)/256, 256, 0, stream>>>(Dw, Dwt);
  prep_x   <<<(T_*B_*F_  +255)/256, 256, 0, stream>>>(inputs, xbf);
  lstm_main<<<256, 1024, 0, stream>>>(xbf, Wt, Wdec, Dwt, bv, bdec, db, hbuf, cnt, out);
}